// Round 1
// baseline (229.180 us; speedup 1.0000x reference)
//
#include <hip/hip_runtime.h>

constexpr float IMG_SIZE = 448.0f;
constexpr float GSZ = 64.0f;           // IMG_SIZE / GRID_NUM
constexpr float LAMBDA_COORD = 5.0f;
constexpr float LAMBDA_NOOBJ = 0.1f;
constexpr float EPSF = 1e-12f;

#define BLOCK 256
#define CPT 4                       // cells per thread
#define TILE (BLOCK * CPT)          // 1024 cells per block

// Faithful port of reference _iou (including the y1_t = cy_t + w_t/2 typo).
__device__ __forceinline__ float iou_one(const float* __restrict__ b,
                                         float tx, float ty, float tw, float th,
                                         float gj, float gi) {
    float cx_p = b[0] * GSZ + gj * GSZ;
    float cy_p = b[1] * GSZ + gi * GSZ;
    float w_p  = b[2] * IMG_SIZE;
    float h_p  = b[3] * IMG_SIZE;
    float x0p = cx_p - 0.5f * w_p, x1p = cx_p + 0.5f * w_p;
    float y0p = cy_p - 0.5f * h_p, y1p = cy_p + 0.5f * h_p;

    float cx_t = tx * GSZ + gj * GSZ;
    float cy_t = ty * GSZ + gi * GSZ;
    float w_t  = tw * IMG_SIZE;
    float h_t  = th * IMG_SIZE;
    float x0t = cx_t - 0.5f * w_t, x1t = cx_t + 0.5f * w_t;
    float y0t = cy_t - 0.5f * h_t;
    float y1t = cy_t + 0.5f * w_t;   // faithful typo: w_t, not h_t

    float ux0 = fmaxf(x0p, x0t), ux1 = fminf(x1p, x1t);
    float uy0 = fmaxf(y0p, y0t), uy1 = fminf(y1p, y1t);
    bool valid = (ux0 < ux1) && (uy0 < uy1);
    float au = (ux1 - ux0) * (uy1 - uy0);
    float ap = (x1p - x0p) * (y1p - y0p);
    float at = (x1t - x0t) * (y1t - y0t);
    float res = au / (ap + at - au + EPSF);
    return valid ? res : 0.0f;
}

// Per-cell loss contribution (caller multiplies by 1/B later).
__device__ __forceinline__ float cell_loss(const float* __restrict__ p,
                                           const float* __restrict__ t,
                                           float gj, float gi) {
    float iou0 = iou_one(p,     t[0], t[1], t[2], t[3], gj, gi);
    float iou1 = iou_one(p + 5, t[0], t[1], t[2], t[3], gj, gi);
    bool obj = (t[4] == 1.0f);
    bool ch0 = iou0 > iou1;
    float loss;
    if (obj) {
        float cp = ch0 ? p[4] : p[9];
        float ct = ch0 ? iou0 : iou1;
        float d  = cp - ct;
        loss = d * d;
        float dx = (ch0 ? p[0] : p[5]) - t[0];
        float dy = (ch0 ? p[1] : p[6]) - t[1];
        loss += LAMBDA_COORD * (dx * dx + dy * dy);
        float wp = fmaxf(ch0 ? p[2] : p[7], EPSF);
        float hp = fmaxf(ch0 ? p[3] : p[8], EPSF);
        float wt = fmaxf(t[2], EPSF);
        float ht = fmaxf(t[3], EPSF);
        float dw = sqrtf(wp) - sqrtf(wt);
        float dh = sqrtf(hp) - sqrtf(ht);
        loss += LAMBDA_COORD * (dw * dw + dh * dh);
    } else {
        loss = LAMBDA_NOOBJ * (p[4] * p[4] + p[9] * p[9]);
    }
    return loss;
}

__global__ __launch_bounds__(BLOCK)
void yolo_loss_kernel(const float* __restrict__ y_pre,
                      const float* __restrict__ y_true,
                      float* __restrict__ out,
                      int cells, float invB) {
    // 1024-cell tile staged with unit-stride float4 loads (coalescing fix).
    __shared__ float s_pre[TILE * 10];     // 40 KB
    __shared__ float s_true[TILE * 5];     // 20 KB

    int tid = threadIdx.x;
    long long base = (long long)blockIdx.x * TILE;
    int n = cells - (int)base;
    if (n > TILE) n = TILE;

    if (n == TILE) {
        // Full tile: lane i reads float4 i -> 1024 B per wave-instruction.
        const float4* gp = (const float4*)(y_pre + base * 10);
        float4* sp = (float4*)s_pre;
        #pragma unroll
        for (int i = 0; i < TILE * 10 / 4 / BLOCK; ++i)      // 10 iters
            sp[i * BLOCK + tid] = gp[i * BLOCK + tid];
        const float4* gt = (const float4*)(y_true + base * 5);
        float4* st = (float4*)s_true;
        #pragma unroll
        for (int i = 0; i < TILE * 5 / 4 / BLOCK; ++i)       // 5 iters
            st[i * BLOCK + tid] = gt[i * BLOCK + tid];
    } else {
        // Partial tail tile (not hit for B=65536, kept for safety).
        for (int f = tid; f < n * 10; f += BLOCK) s_pre[f] = y_pre[base * 10 + f];
        for (int f = tid; f < n * 5;  f += BLOCK) s_true[f] = y_true[base * 5 + f];
    }
    __syncthreads();

    // Compute: thread handles cells {tid, tid+256, tid+512, tid+768} of the
    // tile (stride-256 -> LDS lane-stride 10 dwords, only 4-way conflict).
    float local = 0.0f;
    int rc = (int)((base + tid) % 49);     // cell index within the 7x7 image
    #pragma unroll
    for (int j = 0; j < CPT; ++j) {
        int c = tid + j * BLOCK;
        if (c < n) {
            int gi = rc / 7;
            int gj = rc - gi * 7;
            local += cell_loss(&s_pre[c * 10], &s_true[c * 5],
                               (float)gj, (float)gi);
        }
        rc += (BLOCK % 49);                // 256 % 49 == 11
        if (rc >= 49) rc -= 49;
    }

    // Wave-64 shuffle reduce, then one atomic per block.
    #pragma unroll
    for (int off = 32; off > 0; off >>= 1)
        local += __shfl_down(local, off, 64);

    __shared__ float smem[BLOCK / 64];
    int lane = tid & 63, wid = tid >> 6;
    if (lane == 0) smem[wid] = local;
    __syncthreads();
    if (tid == 0) {
        float s = 0.0f;
        #pragma unroll
        for (int w = 0; w < BLOCK / 64; ++w) s += smem[w];
        atomicAdd(out, s * invB);
    }
}

extern "C" void kernel_launch(void* const* d_in, const int* in_sizes, int n_in,
                              void* d_out, int out_size, void* d_ws, size_t ws_size,
                              hipStream_t stream) {
    const float* y_pre  = (const float*)d_in[0];
    const float* y_true = (const float*)d_in[1];
    float* out = (float*)d_out;

    int cells  = in_sizes[0] / 10;          // B * 7 * 7
    int B      = cells / 49;
    float invB = 1.0f / (float)B;

    hipMemsetAsync(out, 0, sizeof(float), stream);  // d_out is poisoned

    int blocks = (cells + TILE - 1) / TILE;         // 3136 for B=65536
    yolo_loss_kernel<<<blocks, BLOCK, 0, stream>>>(y_pre, y_true, out, cells, invB);
}

// Round 2
// 225.416 us; speedup vs baseline: 1.0167x; 1.0167x over previous
//
#include <hip/hip_runtime.h>

constexpr float IMG_SIZE = 448.0f;
constexpr float GSZ = 64.0f;           // IMG_SIZE / GRID_NUM
constexpr float LAMBDA_COORD = 5.0f;
constexpr float LAMBDA_NOOBJ = 0.1f;
constexpr float EPSF = 1e-12f;

#define BLOCK 256
#define CPT 4                       // cells per thread
#define TILE (BLOCK * CPT)          // 1024 cells per block

// Faithful port of reference _iou (including the y1_t = cy_t + w_t/2 typo).
__device__ __forceinline__ float iou_one(const float* __restrict__ b,
                                         float tx, float ty, float tw, float th,
                                         float gj, float gi) {
    float cx_p = b[0] * GSZ + gj * GSZ;
    float cy_p = b[1] * GSZ + gi * GSZ;
    float w_p  = b[2] * IMG_SIZE;
    float h_p  = b[3] * IMG_SIZE;
    float x0p = cx_p - 0.5f * w_p, x1p = cx_p + 0.5f * w_p;
    float y0p = cy_p - 0.5f * h_p, y1p = cy_p + 0.5f * h_p;

    float cx_t = tx * GSZ + gj * GSZ;
    float cy_t = ty * GSZ + gi * GSZ;
    float w_t  = tw * IMG_SIZE;
    float h_t  = th * IMG_SIZE;
    float x0t = cx_t - 0.5f * w_t, x1t = cx_t + 0.5f * w_t;
    float y0t = cy_t - 0.5f * h_t;
    float y1t = cy_t + 0.5f * w_t;   // faithful typo: w_t, not h_t

    float ux0 = fmaxf(x0p, x0t), ux1 = fminf(x1p, x1t);
    float uy0 = fmaxf(y0p, y0t), uy1 = fminf(y1p, y1t);
    bool valid = (ux0 < ux1) && (uy0 < uy1);
    float au = (ux1 - ux0) * (uy1 - uy0);
    float ap = (x1p - x0p) * (y1p - y0p);
    float at = (x1t - x0t) * (y1t - y0t);
    float res = au / (ap + at - au + EPSF);
    return valid ? res : 0.0f;
}

// Per-cell loss contribution (unscaled; reduce kernel applies 1/B).
__device__ __forceinline__ float cell_loss(const float* __restrict__ p,
                                           const float* __restrict__ t,
                                           float gj, float gi) {
    float iou0 = iou_one(p,     t[0], t[1], t[2], t[3], gj, gi);
    float iou1 = iou_one(p + 5, t[0], t[1], t[2], t[3], gj, gi);
    bool obj = (t[4] == 1.0f);
    bool ch0 = iou0 > iou1;
    float loss;
    if (obj) {
        float cp = ch0 ? p[4] : p[9];
        float ct = ch0 ? iou0 : iou1;
        float d  = cp - ct;
        loss = d * d;
        float dx = (ch0 ? p[0] : p[5]) - t[0];
        float dy = (ch0 ? p[1] : p[6]) - t[1];
        loss += LAMBDA_COORD * (dx * dx + dy * dy);
        float wp = fmaxf(ch0 ? p[2] : p[7], EPSF);
        float hp = fmaxf(ch0 ? p[3] : p[8], EPSF);
        float wt = fmaxf(t[2], EPSF);
        float ht = fmaxf(t[3], EPSF);
        float dw = sqrtf(wp) - sqrtf(wt);
        float dh = sqrtf(hp) - sqrtf(ht);
        loss += LAMBDA_COORD * (dw * dw + dh * dh);
    } else {
        loss = LAMBDA_NOOBJ * (p[4] * p[4] + p[9] * p[9]);
    }
    return loss;
}

__global__ __launch_bounds__(BLOCK)
void yolo_loss_kernel(const float* __restrict__ y_pre,
                      const float* __restrict__ y_true,
                      float* __restrict__ partials,
                      int cells) {
    // 1024-cell tile staged with unit-stride float4 loads.
    __shared__ float s_pre[TILE * 10];     // 40 KB
    __shared__ float s_true[TILE * 5];     // 20 KB

    int tid = threadIdx.x;
    long long base = (long long)blockIdx.x * TILE;
    int n = cells - (int)base;
    if (n > TILE) n = TILE;

    if (n == TILE) {
        // Full tile: lane i reads float4 i -> 1024 B per wave-instruction.
        const float4* gp = (const float4*)(y_pre + base * 10);
        float4* sp = (float4*)s_pre;
        #pragma unroll
        for (int i = 0; i < TILE * 10 / 4 / BLOCK; ++i)      // 10 iters
            sp[i * BLOCK + tid] = gp[i * BLOCK + tid];
        const float4* gt = (const float4*)(y_true + base * 5);
        float4* st = (float4*)s_true;
        #pragma unroll
        for (int i = 0; i < TILE * 5 / 4 / BLOCK; ++i)       // 5 iters
            st[i * BLOCK + tid] = gt[i * BLOCK + tid];
    } else {
        // Partial tail tile (not hit for B=65536, kept for safety).
        for (int f = tid; f < n * 10; f += BLOCK) s_pre[f] = y_pre[base * 10 + f];
        for (int f = tid; f < n * 5;  f += BLOCK) s_true[f] = y_true[base * 5 + f];
    }
    __syncthreads();

    // Compute: thread handles cells {tid, tid+256, tid+512, tid+768} of the
    // tile (stride-256 -> LDS lane-stride 10 dwords, only 4-way conflict).
    float local = 0.0f;
    int rc = (int)((base + tid) % 49);     // cell index within the 7x7 image
    #pragma unroll
    for (int j = 0; j < CPT; ++j) {
        int c = tid + j * BLOCK;
        if (c < n) {
            int gi = rc / 7;
            int gj = rc - gi * 7;
            local += cell_loss(&s_pre[c * 10], &s_true[c * 5],
                               (float)gj, (float)gi);
        }
        rc += (BLOCK % 49);                // 256 % 49 == 11
        if (rc >= 49) rc -= 49;
    }

    // Wave-64 shuffle reduce; ONE PLAIN STORE per block (no atomic chain).
    #pragma unroll
    for (int off = 32; off > 0; off >>= 1)
        local += __shfl_down(local, off, 64);

    __shared__ float smem[BLOCK / 64];
    int lane = tid & 63, wid = tid >> 6;
    if (lane == 0) smem[wid] = local;
    __syncthreads();
    if (tid == 0) {
        float s = 0.0f;
        #pragma unroll
        for (int w = 0; w < BLOCK / 64; ++w) s += smem[w];
        partials[blockIdx.x] = s;
    }
}

// One block reduces the per-block partials and writes the final scaled loss.
__global__ __launch_bounds__(256)
void reduce_kernel(const float* __restrict__ partials,
                   float* __restrict__ out,
                   int n, float invB) {
    int tid = threadIdx.x;
    float local = 0.0f;
    for (int i = tid; i < n; i += 256) local += partials[i];

    #pragma unroll
    for (int off = 32; off > 0; off >>= 1)
        local += __shfl_down(local, off, 64);

    __shared__ float smem[4];
    int lane = tid & 63, wid = tid >> 6;
    if (lane == 0) smem[wid] = local;
    __syncthreads();
    if (tid == 0)
        out[0] = (smem[0] + smem[1] + smem[2] + smem[3]) * invB;
}

extern "C" void kernel_launch(void* const* d_in, const int* in_sizes, int n_in,
                              void* d_out, int out_size, void* d_ws, size_t ws_size,
                              hipStream_t stream) {
    const float* y_pre  = (const float*)d_in[0];
    const float* y_true = (const float*)d_in[1];
    float* out = (float*)d_out;
    float* partials = (float*)d_ws;

    int cells  = in_sizes[0] / 10;          // B * 7 * 7
    int B      = cells / 49;
    float invB = 1.0f / (float)B;

    int blocks = (cells + TILE - 1) / TILE;         // 3136 for B=65536

    yolo_loss_kernel<<<blocks, BLOCK, 0, stream>>>(y_pre, y_true, partials, cells);
    reduce_kernel<<<1, 256, 0, stream>>>(partials, out, blocks, invB);
}